// Round 8
// baseline (190.448 us; speedup 1.0000x reference)
//
#include <hip/hip_runtime.h>

// Problem constants
#define B_      4
#define CIN     128
#define COUT    128
#define HW      256          // 16*16
#define WN      147456       // 128*128*9
#define WPK     1152         // per-co kernel elems = 128*9
#define ADIM    16

// ws float layout (scalars)
#define WS_A     0            // A[b][k], 4*7
#define WS_S1    28
#define WS_S0    29
#define WS_BO    30
// ws byte layout (bf16 tensors)
#define MWT_OFF  4096                         // mwT[b][j][co][ci] bf16: 4*9*128*128
#define XT_OFF   (4096 + 4*9*128*128*2)       // xT[b][18][18][ci] bf16: 4*324*128

typedef __attribute__((ext_vector_type(8))) short bf16x8;
typedef __attribute__((ext_vector_type(4))) float f32x4;

__device__ __forceinline__ unsigned short f2bf(float f) {
    union { float f; unsigned int u; } v; v.f = f;
    unsigned int u = v.u;
    return (unsigned short)((u + 0x7FFFu + ((u >> 16) & 1u)) >> 16);  // RNE
}

__device__ __forceinline__ float waveReduceSum(float v) {
    #pragma unroll
    for (int off = 32; off; off >>= 1) v += __shfl_down(v, off, 64);
    return v;
}

// 1024-thread block sum, broadcast. Safe to call repeatedly.
__device__ __forceinline__ float blockSum1024(float v, float* tmp16, int tid) {
    v = waveReduceSum(v);
    __syncthreads();
    if ((tid & 63) == 0) tmp16[tid >> 6] = v;
    __syncthreads();
    float s = 0.f;
    #pragma unroll
    for (int i = 0; i < 16; ++i) s += tmp16[i];
    return s;
}

// K_HEAD: one block per batch b (1024 threads).
// Redundantly computes w-moments S1..S6 (36 float4/thread), tiny projections,
// alpha per pixel, Z via deg-6 Taylor of moments, and A_k[b] reductions.
__global__ __launch_bounds__(1024) void k_head(
        const float* __restrict__ x, const float* __restrict__ w,
        const float* __restrict__ fcq,  const float* __restrict__ fcqb,
        const float* __restrict__ fck,
        const float* __restrict__ fcv,  const float* __restrict__ fcvb,
        const float* __restrict__ fco,  const float* __restrict__ fcob,
        float* __restrict__ ws) {
    __shared__ float tmp16[16];
    __shared__ float S[7];
    __shared__ float gl[128];
    __shared__ float g0s;
    __shared__ float psum[4][256];
    const int tid = threadIdx.x, b = blockIdx.x;

    // ---- moments of wflat (each block does the full sum; w is L2-resident) ----
    const float4* w4 = reinterpret_cast<const float4*>(w);
    float m[6] = {0.f, 0.f, 0.f, 0.f, 0.f, 0.f};
    #pragma unroll
    for (int i = 0; i < 36; ++i) {
        float4 v4 = w4[i * 1024 + tid];
        float vals[4] = {v4.x, v4.y, v4.z, v4.w};
        #pragma unroll
        for (int e = 0; e < 4; ++e) {
            float v = vals[e], v2 = v * v, v3 = v2 * v;
            m[0] += v; m[1] += v2; m[2] += v3;
            m[3] += v2 * v2; m[4] += v2 * v3; m[5] += v3 * v3;
        }
    }
    #pragma unroll
    for (int k = 0; k < 6; ++k) {
        float s = blockSum1024(m[k], tmp16, tid);
        if (tid == 0) S[k + 1] = s;
    }

    // ---- tiny projections ----
    if (tid < 128) {                 // g[c] = sum_a Wq[a,c] * fk[a]
        float s = 0.f;
        #pragma unroll
        for (int a = 0; a < ADIM; ++a) s += fcq[a * CIN + tid] * fck[a];
        gl[tid] = s;
    } else if (tid == 128) {
        float s = 0.f;
        for (int a = 0; a < ADIM; ++a) s += fcqb[a] * fck[a];
        g0s = s;
    } else if (tid == 129) {         // s1 = fv . fo  (same value written by all 4 blocks)
        float s = 0.f;
        for (int a = 0; a < ADIM; ++a) s += fcv[a] * fco[a];
        ws[WS_S1] = s;
    } else if (tid == 130) {         // s0 = bv . fo
        float s = 0.f;
        for (int a = 0; a < ADIM; ++a) s += fcvb[a] * fco[a];
        ws[WS_S0] = s;
    } else if (tid == 131) {
        ws[WS_BO] = fcob[0];
    }
    __syncthreads();

    // ---- alpha per pixel: (g . x[b,:,p] + g0) / 4 ----
    const int p = tid & 255, cg = tid >> 8;
    float dot = 0.f;
    const float* xb = x + (size_t)b * CIN * HW + p;
    const int c0 = cg * 32;
    #pragma unroll 8
    for (int c = 0; c < 32; ++c) dot += xb[(c0 + c) * HW] * gl[c0 + c];
    psum[cg][p] = dot;
    __syncthreads();

    float alpha = 0.f, r = 0.f;
    if (cg == 0) {
        alpha = (psum[0][p] + psum[1][p] + psum[2][p] + psum[3][p] + g0s) * 0.25f;
        // Z(alpha): deg-6 Taylor via raw moments (|alpha*w| << 1)
        float Z = S[6] * (1.f / 720.f);
        Z = Z * alpha + S[5] * (1.f / 120.f);
        Z = Z * alpha + S[4] * (1.f / 24.f);
        Z = Z * alpha + S[3] * (1.f / 6.f);
        Z = Z * alpha + S[2] * 0.5f;
        Z = Z * alpha + S[1];
        Z = Z * alpha + (float)WN;
        r = 1.0f / ((float)HW * Z);
    }
    // A_k[b] = sum_q r_q * alpha_q^k / k!
    float t = r;
    const float invk[7] = {1.f, 1.f, 0.5f, 1.f / 3.f, 0.25f, 0.2f, 1.f / 6.f};
    #pragma unroll
    for (int k = 0; k < 7; ++k) {
        float s = blockSum1024(t, tmp16, tid);
        if (tid == 0) ws[WS_A + b * 7 + k] = s;
        t = t * alpha * invk[k + 1 > 6 ? 6 : k + 1];
    }
}

// K_MX: blocks 0..31 -> masked weights bf16 transposed [b][j][co][ci];
//       blocks 32..35 -> x bf16 zero-padded transpose [b][18][18][ci]
__global__ __launch_bounds__(256) void k_mx(
        const float* __restrict__ x, const float* __restrict__ w,
        const float* __restrict__ ws, const float* __restrict__ gamma,
        unsigned short* __restrict__ mwT, unsigned short* __restrict__ xT) {
    const int tid = threadIdx.x;
    if (blockIdx.x < 32) {
        const int b = blockIdx.x >> 3, chunk = blockIdx.x & 7;
        const float A0 = ws[WS_A + b * 7 + 0], A1 = ws[WS_A + b * 7 + 1];
        const float A2 = ws[WS_A + b * 7 + 2], A3 = ws[WS_A + b * 7 + 3];
        const float A4 = ws[WS_A + b * 7 + 4], A5 = ws[WS_A + b * 7 + 5];
        const float A6 = ws[WS_A + b * 7 + 6];
        const float s1 = ws[WS_S1], s0 = ws[WS_S0], bo = ws[WS_BO];
        const float gam = gamma[0];
        const int end = chunk * 2048 + 2048;
        for (int i = chunk * 2048 + tid; i < end; i += 256) {
            const int co = i >> 7, ci = i & 127;
            const float* wp = w + co * WPK + ci * 9;
            #pragma unroll
            for (int j = 0; j < 9; ++j) {
                float wv = wp[j];
                float pp = A6;
                pp = pp * wv + A5; pp = pp * wv + A4; pp = pp * wv + A3;
                pp = pp * wv + A2; pp = pp * wv + A1; pp = pp * wv + A0;
                float mwv = wv + gam * (pp * (s1 * wv + s0) + bo);
                mwT[(((b * 9 + j) << 7 | co) << 7) | ci] = f2bf(mwv);
            }
        }
    } else {
        const int b = blockIdx.x - 32;
        if (tid < 68) {                 // zero halo border pixel-slots
            int rr, cc;
            if (tid < 18)      { rr = 0;            cc = tid; }
            else if (tid < 36) { rr = 17;           cc = tid - 18; }
            else if (tid < 52) { rr = tid - 36 + 1; cc = 0; }
            else               { rr = tid - 52 + 1; cc = 17; }
            unsigned short* dst = xT + ((size_t)b * 324 + rr * 18 + cc) * 128;
            bf16x8 z = {};
            #pragma unroll
            for (int i = 0; i < 16; ++i) *reinterpret_cast<bf16x8*>(dst + i * 8) = z;
        }
        const int py = tid >> 4, px = tid & 15;
        const float* xb = x + (size_t)b * CIN * HW + tid;
        unsigned short* dst = xT + ((size_t)b * 324 + (py + 1) * 18 + (px + 1)) * 128;
        for (int ci0 = 0; ci0 < 128; ci0 += 8) {
            bf16x8 pk;
            #pragma unroll
            for (int e = 0; e < 8; ++e) pk[e] = (short)f2bf(xb[(ci0 + e) * HW]);
            *reinterpret_cast<bf16x8*>(dst + ci0) = pk;
        }
    }
}

// K_CONV: shifted implicit-GEMM, MFMA bf16, no LDS. 128 blocks x 1 wave.
// wave tile: 32 co x 32 p; D[m=co][n=pixel] = sum_j sum_ci mwT * xT(shift j)
__global__ __launch_bounds__(64) void k_conv_mfma(
        const unsigned short* __restrict__ mwT,
        const unsigned short* __restrict__ xT,
        float* __restrict__ out) {
    const int wgid = blockIdx.x;          // 128 wave-tiles
    const int l = threadIdx.x;            // 0..63
    const int b = wgid >> 5;
    const int rem = wgid & 31;
    const int cobase = (rem >> 3) * 32;
    const int pbase  = (rem & 7) * 32;
    const int lr = l & 15, lk = l >> 4;

    const int p0 = pbase + lr,       p1 = pbase + 16 + lr;
    const int py0 = p0 >> 4, px0 = p0 & 15;
    const int py1 = p1 >> 4, px1 = p1 & 15;

    f32x4 acc[2][2] = {};

    #pragma unroll 3
    for (int j = 0; j < 9; ++j) {
        const int dy = j / 3, dx = j % 3;
        const unsigned short* ab = mwT + (((b * 9 + j) * 128 + cobase + lr) * 128 + lk * 8);
        const unsigned short* bb0 = xT + (((size_t)b * 324 + (py0 + dy) * 18 + (px0 + dx)) * 128 + lk * 8);
        const unsigned short* bb1 = xT + (((size_t)b * 324 + (py1 + dy) * 18 + (px1 + dx)) * 128 + lk * 8);
        #pragma unroll
        for (int c = 0; c < 4; ++c) {     // ci chunk of 32
            bf16x8 a0 = *reinterpret_cast<const bf16x8*>(ab + c * 32);
            bf16x8 a1 = *reinterpret_cast<const bf16x8*>(ab + 16 * 128 + c * 32);
            bf16x8 vb0 = *reinterpret_cast<const bf16x8*>(bb0 + c * 32);
            bf16x8 vb1 = *reinterpret_cast<const bf16x8*>(bb1 + c * 32);
            acc[0][0] = __builtin_amdgcn_mfma_f32_16x16x32_bf16(a0, vb0, acc[0][0], 0, 0, 0);
            acc[0][1] = __builtin_amdgcn_mfma_f32_16x16x32_bf16(a0, vb1, acc[0][1], 0, 0, 0);
            acc[1][0] = __builtin_amdgcn_mfma_f32_16x16x32_bf16(a1, vb0, acc[1][0], 0, 0, 0);
            acc[1][1] = __builtin_amdgcn_mfma_f32_16x16x32_bf16(a1, vb1, acc[1][1], 0, 0, 0);
        }
    }
    // C/D layout: col(n=pixel)=lane&15, row(m=co)=(lane>>4)*4+reg
    #pragma unroll
    for (int s = 0; s < 2; ++s)
        #pragma unroll
        for (int t = 0; t < 2; ++t)
            #pragma unroll
            for (int r = 0; r < 4; ++r) {
                const int co = cobase + s * 16 + lk * 4 + r;
                const int p  = pbase + t * 16 + lr;
                out[((size_t)b * COUT + co) * HW + p] = acc[s][t][r];
            }
}

extern "C" void kernel_launch(void* const* d_in, const int* in_sizes, int n_in,
                              void* d_out, int out_size, void* d_ws, size_t ws_size,
                              hipStream_t stream) {
    const float* x    = (const float*)d_in[0];
    const float* wt   = (const float*)d_in[1];
    const float* fcq  = (const float*)d_in[2];
    const float* fcqb = (const float*)d_in[3];
    const float* fck  = (const float*)d_in[4];
    // d_in[5] = fc_k_b: cancels in softmax over n -- unused
    const float* fcv  = (const float*)d_in[6];
    const float* fcvb = (const float*)d_in[7];
    const float* fco  = (const float*)d_in[8];
    const float* fcob = (const float*)d_in[9];
    const float* gam  = (const float*)d_in[10];
    float* ws  = (float*)d_ws;
    unsigned short* mwT = (unsigned short*)((char*)d_ws + MWT_OFF);
    unsigned short* xT  = (unsigned short*)((char*)d_ws + XT_OFF);
    float* out = (float*)d_out;

    hipLaunchKernelGGL(k_head, dim3(B_), dim3(1024), 0, stream,
                       x, wt, fcq, fcqb, fck, fcv, fcvb, fco, fcob, ws);
    hipLaunchKernelGGL(k_mx, dim3(36), dim3(256), 0, stream, x, wt, ws, gam, mwT, xT);
    hipLaunchKernelGGL(k_conv_mfma, dim3(128), dim3(64), 0, stream, mwT, xT, out);
}

// Round 10
// 109.272 us; speedup vs baseline: 1.7429x; 1.7429x over previous
//
#include <hip/hip_runtime.h>

// Problem constants
#define B_      4
#define CIN     128
#define COUT    128
#define HW      256          // 16*16
#define WN      147456       // 128*128*9
#define WPK     1152         // per-co kernel elems = 128*9
#define ADIM    16

// ws float layout (scalars)
#define WS_A     0            // A[b][k], 4*7
#define WS_S1    28
#define WS_S0    29
#define WS_BO    30
// ws byte layout (bf16 tensors)
#define MWT_OFF  4096                         // mwT[b][j][co][ci] bf16: 4*9*128*128
#define XT_OFF   (4096 + 4*9*128*128*2)       // xT[b][18][18][ci] bf16: 4*324*128

typedef __attribute__((ext_vector_type(8))) short bf16x8;
typedef __attribute__((ext_vector_type(4))) float f32x4;

__device__ __forceinline__ unsigned short f2bf(float f) {
    union { float f; unsigned int u; } v; v.f = f;
    unsigned int u = v.u;
    return (unsigned short)((u + 0x7FFFu + ((u >> 16) & 1u)) >> 16);  // RNE
}

__device__ __forceinline__ float waveReduceSum(float v) {
    #pragma unroll
    for (int off = 32; off; off >>= 1) v += __shfl_down(v, off, 64);
    return v;
}

// 1024-thread block sum, broadcast. Safe to call repeatedly.
__device__ __forceinline__ float blockSum1024(float v, float* tmp16, int tid) {
    v = waveReduceSum(v);
    __syncthreads();
    if ((tid & 63) == 0) tmp16[tid >> 6] = v;
    __syncthreads();
    float s = 0.f;
    #pragma unroll
    for (int i = 0; i < 16; ++i) s += tmp16[i];
    return s;
}

// K_HEAD: one block per batch b (1024 threads, 1 block/CU -> 128 VGPR budget).
// Moment loop unroll-capped to 2: live state ~2xfloat4 + 6 accumulators, so no
// scratch spill (Round-8 pathology: full unroll @64 VGPR -> 3.7MB spill traffic,
// 127us latency crawl).
__global__ __launch_bounds__(1024, 4) void k_head(
        const float* __restrict__ x, const float* __restrict__ w,
        const float* __restrict__ fcq,  const float* __restrict__ fcqb,
        const float* __restrict__ fck,
        const float* __restrict__ fcv,  const float* __restrict__ fcvb,
        const float* __restrict__ fco,  const float* __restrict__ fcob,
        float* __restrict__ ws) {
    __shared__ float tmp16[16];
    __shared__ float S[7];
    __shared__ float gl[128];
    __shared__ float g0s;
    __shared__ float psum[4][256];
    const int tid = threadIdx.x, b = blockIdx.x;

    // ---- moments of wflat (each block does the full sum; w is L2-resident) ----
    const float4* w4 = reinterpret_cast<const float4*>(w);
    float m[6] = {0.f, 0.f, 0.f, 0.f, 0.f, 0.f};
    #pragma unroll 2
    for (int i = 0; i < 36; ++i) {
        float4 v4 = w4[i * 1024 + tid];
        float vals[4] = {v4.x, v4.y, v4.z, v4.w};
        #pragma unroll
        for (int e = 0; e < 4; ++e) {
            float v = vals[e], v2 = v * v, v3 = v2 * v;
            m[0] += v; m[1] += v2; m[2] += v3;
            m[3] += v2 * v2; m[4] += v2 * v3; m[5] += v3 * v3;
        }
    }
    #pragma unroll
    for (int k = 0; k < 6; ++k) {
        float s = blockSum1024(m[k], tmp16, tid);
        if (tid == 0) S[k + 1] = s;
    }

    // ---- tiny projections ----
    if (tid < 128) {                 // g[c] = sum_a Wq[a,c] * fk[a]
        float s = 0.f;
        #pragma unroll
        for (int a = 0; a < ADIM; ++a) s += fcq[a * CIN + tid] * fck[a];
        gl[tid] = s;
    } else if (tid == 128) {
        float s = 0.f;
        for (int a = 0; a < ADIM; ++a) s += fcqb[a] * fck[a];
        g0s = s;
    } else if (tid == 129) {         // s1 = fv . fo  (same value written by all 4 blocks)
        float s = 0.f;
        for (int a = 0; a < ADIM; ++a) s += fcv[a] * fco[a];
        ws[WS_S1] = s;
    } else if (tid == 130) {         // s0 = bv . fo
        float s = 0.f;
        for (int a = 0; a < ADIM; ++a) s += fcvb[a] * fco[a];
        ws[WS_S0] = s;
    } else if (tid == 131) {
        ws[WS_BO] = fcob[0];
    }
    __syncthreads();

    // ---- alpha per pixel: (g . x[b,:,p] + g0) / 4 ----
    const int p = tid & 255, cg = tid >> 8;
    float dot = 0.f;
    const float* xb = x + (size_t)b * CIN * HW + p;
    const int c0 = cg * 32;
    #pragma unroll 8
    for (int c = 0; c < 32; ++c) dot += xb[(c0 + c) * HW] * gl[c0 + c];
    psum[cg][p] = dot;
    __syncthreads();

    float alpha = 0.f, r = 0.f;
    if (cg == 0) {
        alpha = (psum[0][p] + psum[1][p] + psum[2][p] + psum[3][p] + g0s) * 0.25f;
        // Z(alpha): deg-6 Taylor via raw moments (|alpha*w| << 1)
        float Z = S[6] * (1.f / 720.f);
        Z = Z * alpha + S[5] * (1.f / 120.f);
        Z = Z * alpha + S[4] * (1.f / 24.f);
        Z = Z * alpha + S[3] * (1.f / 6.f);
        Z = Z * alpha + S[2] * 0.5f;
        Z = Z * alpha + S[1];
        Z = Z * alpha + (float)WN;
        r = 1.0f / ((float)HW * Z);
    }
    // A_k[b] = sum_q r_q * alpha_q^k / k!
    float t = r;
    const float invk[7] = {1.f, 1.f, 0.5f, 1.f / 3.f, 0.25f, 0.2f, 1.f / 6.f};
    #pragma unroll
    for (int k = 0; k < 7; ++k) {
        float s = blockSum1024(t, tmp16, tid);
        if (tid == 0) ws[WS_A + b * 7 + k] = s;
        t = t * alpha * invk[k + 1 > 6 ? 6 : k + 1];
    }
}

// K_MX: blocks 0..31 -> masked weights bf16 transposed [b][j][co][ci];
//       blocks 32..35 -> x bf16 zero-padded transpose [b][18][18][ci]
__global__ __launch_bounds__(256) void k_mx(
        const float* __restrict__ x, const float* __restrict__ w,
        const float* __restrict__ ws, const float* __restrict__ gamma,
        unsigned short* __restrict__ mwT, unsigned short* __restrict__ xT) {
    const int tid = threadIdx.x;
    if (blockIdx.x < 32) {
        const int b = blockIdx.x >> 3, chunk = blockIdx.x & 7;
        const float A0 = ws[WS_A + b * 7 + 0], A1 = ws[WS_A + b * 7 + 1];
        const float A2 = ws[WS_A + b * 7 + 2], A3 = ws[WS_A + b * 7 + 3];
        const float A4 = ws[WS_A + b * 7 + 4], A5 = ws[WS_A + b * 7 + 5];
        const float A6 = ws[WS_A + b * 7 + 6];
        const float s1 = ws[WS_S1], s0 = ws[WS_S0], bo = ws[WS_BO];
        const float gam = gamma[0];
        const int end = chunk * 2048 + 2048;
        for (int i = chunk * 2048 + tid; i < end; i += 256) {
            const int co = i >> 7, ci = i & 127;
            const float* wp = w + co * WPK + ci * 9;
            #pragma unroll
            for (int j = 0; j < 9; ++j) {
                float wv = wp[j];
                float pp = A6;
                pp = pp * wv + A5; pp = pp * wv + A4; pp = pp * wv + A3;
                pp = pp * wv + A2; pp = pp * wv + A1; pp = pp * wv + A0;
                float mwv = wv + gam * (pp * (s1 * wv + s0) + bo);
                mwT[(((b * 9 + j) << 7 | co) << 7) | ci] = f2bf(mwv);
            }
        }
    } else {
        const int b = blockIdx.x - 32;
        if (tid < 68) {                 // zero halo border pixel-slots
            int rr, cc;
            if (tid < 18)      { rr = 0;            cc = tid; }
            else if (tid < 36) { rr = 17;           cc = tid - 18; }
            else if (tid < 52) { rr = tid - 36 + 1; cc = 0; }
            else               { rr = tid - 52 + 1; cc = 17; }
            unsigned short* dst = xT + ((size_t)b * 324 + rr * 18 + cc) * 128;
            bf16x8 z = {};
            #pragma unroll
            for (int i = 0; i < 16; ++i) *reinterpret_cast<bf16x8*>(dst + i * 8) = z;
        }
        const int py = tid >> 4, px = tid & 15;
        const float* xb = x + (size_t)b * CIN * HW + tid;
        unsigned short* dst = xT + ((size_t)b * 324 + (py + 1) * 18 + (px + 1)) * 128;
        for (int ci0 = 0; ci0 < 128; ci0 += 8) {
            bf16x8 pk;
            #pragma unroll
            for (int e = 0; e < 8; ++e) pk[e] = (short)f2bf(xb[(ci0 + e) * HW]);
            *reinterpret_cast<bf16x8*>(dst + ci0) = pk;
        }
    }
}

// K_CONV: shifted implicit-GEMM, MFMA bf16, no LDS. 128 blocks x 1 wave.
// wave tile: 32 co x 32 p; D[m=co][n=pixel] = sum_j sum_ci mwT * xT(shift j)
__global__ __launch_bounds__(64) void k_conv_mfma(
        const unsigned short* __restrict__ mwT,
        const unsigned short* __restrict__ xT,
        float* __restrict__ out) {
    const int wgid = blockIdx.x;          // 128 wave-tiles
    const int l = threadIdx.x;            // 0..63
    const int b = wgid >> 5;
    const int rem = wgid & 31;
    const int cobase = (rem >> 3) * 32;
    const int pbase  = (rem & 7) * 32;
    const int lr = l & 15, lk = l >> 4;

    const int p0 = pbase + lr,       p1 = pbase + 16 + lr;
    const int py0 = p0 >> 4, px0 = p0 & 15;
    const int py1 = p1 >> 4, px1 = p1 & 15;

    f32x4 acc[2][2] = {};

    #pragma unroll 3
    for (int j = 0; j < 9; ++j) {
        const int dy = j / 3, dx = j % 3;
        const unsigned short* ab = mwT + (((b * 9 + j) * 128 + cobase + lr) * 128 + lk * 8);
        const unsigned short* bb0 = xT + (((size_t)b * 324 + (py0 + dy) * 18 + (px0 + dx)) * 128 + lk * 8);
        const unsigned short* bb1 = xT + (((size_t)b * 324 + (py1 + dy) * 18 + (px1 + dx)) * 128 + lk * 8);
        #pragma unroll
        for (int c = 0; c < 4; ++c) {     // ci chunk of 32
            bf16x8 a0 = *reinterpret_cast<const bf16x8*>(ab + c * 32);
            bf16x8 a1 = *reinterpret_cast<const bf16x8*>(ab + 16 * 128 + c * 32);
            bf16x8 vb0 = *reinterpret_cast<const bf16x8*>(bb0 + c * 32);
            bf16x8 vb1 = *reinterpret_cast<const bf16x8*>(bb1 + c * 32);
            acc[0][0] = __builtin_amdgcn_mfma_f32_16x16x32_bf16(a0, vb0, acc[0][0], 0, 0, 0);
            acc[0][1] = __builtin_amdgcn_mfma_f32_16x16x32_bf16(a0, vb1, acc[0][1], 0, 0, 0);
            acc[1][0] = __builtin_amdgcn_mfma_f32_16x16x32_bf16(a1, vb0, acc[1][0], 0, 0, 0);
            acc[1][1] = __builtin_amdgcn_mfma_f32_16x16x32_bf16(a1, vb1, acc[1][1], 0, 0, 0);
        }
    }
    // C/D layout: col(n=pixel)=lane&15, row(m=co)=(lane>>4)*4+reg
    #pragma unroll
    for (int s = 0; s < 2; ++s)
        #pragma unroll
        for (int t = 0; t < 2; ++t)
            #pragma unroll
            for (int r = 0; r < 4; ++r) {
                const int co = cobase + s * 16 + lk * 4 + r;
                const int p  = pbase + t * 16 + lr;
                out[((size_t)b * COUT + co) * HW + p] = acc[s][t][r];
            }
}

extern "C" void kernel_launch(void* const* d_in, const int* in_sizes, int n_in,
                              void* d_out, int out_size, void* d_ws, size_t ws_size,
                              hipStream_t stream) {
    const float* x    = (const float*)d_in[0];
    const float* wt   = (const float*)d_in[1];
    const float* fcq  = (const float*)d_in[2];
    const float* fcqb = (const float*)d_in[3];
    const float* fck  = (const float*)d_in[4];
    // d_in[5] = fc_k_b: cancels in softmax over n -- unused
    const float* fcv  = (const float*)d_in[6];
    const float* fcvb = (const float*)d_in[7];
    const float* fco  = (const float*)d_in[8];
    const float* fcob = (const float*)d_in[9];
    const float* gam  = (const float*)d_in[10];
    float* ws  = (float*)d_ws;
    unsigned short* mwT = (unsigned short*)((char*)d_ws + MWT_OFF);
    unsigned short* xT  = (unsigned short*)((char*)d_ws + XT_OFF);
    float* out = (float*)d_out;

    hipLaunchKernelGGL(k_head, dim3(B_), dim3(1024), 0, stream,
                       x, wt, fcq, fcqb, fck, fcv, fcvb, fco, fcob, ws);
    hipLaunchKernelGGL(k_mx, dim3(36), dim3(256), 0, stream, x, wt, ws, gam, mwT, xT);
    hipLaunchKernelGGL(k_conv_mfma, dim3(128), dim3(64), 0, stream, mwT, xT, out);
}